// Round 5
// baseline (324.768 us; speedup 1.0000x reference)
//
#include <hip/hip_runtime.h>
#include <hip/hip_bf16.h>
#include <cstdint>
#include <cstddef>

#define Z 256      // latent dim (K)
#define CG 128     // e-columns per block
#define RT 64      // mean-rows per tile
#define NCH 8      // N chunks (grid = 64 x 8 = 512 = exactly 2 blocks/CU)
#define LOG2E 1.4426950408889634f
#define LN2 0.6931471805599453f

typedef __attribute__((ext_vector_type(8))) short short8_t;
typedef __attribute__((ext_vector_type(4))) float f32x4;

#define GLOAD_LDS16(g, l)                                                              \
  __builtin_amdgcn_global_load_lds((const __attribute__((address_space(1))) void*)(g), \
                                   (__attribute__((address_space(3))) void*)(l), 16, 0, 0)

__device__ __forceinline__ unsigned short f2bf(float x) {
  __hip_bfloat16 h = __float2bfloat16(x);
  return *reinterpret_cast<unsigned short*>(&h);
}

__device__ __forceinline__ float fast_exp2(float x) {
  float r;
  asm("v_exp_f32 %0, %1" : "=v"(r) : "v"(x));
  return r;
}

// prep: fp32 -> bf16 scaled by sqrt(c1), plus k2 * row-sum-of-squares.
// 16 rows/block, one 16-lane group per row.
__global__ __launch_bounds__(256) void prep_kernel(const float* __restrict__ mean,
                                                   const float* __restrict__ e,
                                                   unsigned short* __restrict__ Abf,
                                                   unsigned short* __restrict__ Bbf,
                                                   float* __restrict__ nrm,
                                                   const int* __restrict__ sigma_p,
                                                   int Nr, int Mr) {
  const float sgm = (float)(*sigma_p);
  const float c1 = LOG2E / (sgm * sgm);
  const float k2 = 0.5f * c1;
  const float sc = sqrtf(c1);
  const int tid = threadIdx.x;
  const int lane16 = tid & 15;
  const int row = blockIdx.x * 16 + (tid >> 4);
  if (row >= Nr + Mr) return;
  const float* src = (row < Nr) ? (mean + (size_t)row * Z) : (e + (size_t)(row - Nr) * Z);
  unsigned short* d = (row < Nr) ? (Abf + (size_t)row * Z) : (Bbf + (size_t)(row - Nr) * Z);
  float4 v[4];
  float s = 0.f;
#pragma unroll
  for (int i = 0; i < 4; ++i) {
    v[i] = *reinterpret_cast<const float4*>(src + (lane16 + i * 16) * 4);
    s += v[i].x * v[i].x + v[i].y * v[i].y + v[i].z * v[i].z + v[i].w * v[i].w;
  }
  s += __shfl_xor(s, 1); s += __shfl_xor(s, 2);
  s += __shfl_xor(s, 4); s += __shfl_xor(s, 8);
  if (lane16 == 0) nrm[row] = k2 * s;
#pragma unroll
  for (int i = 0; i < 4; ++i) {
    ushort4 o;
    o.x = f2bf(v[i].x * sc); o.y = f2bf(v[i].y * sc);
    o.z = f2bf(v[i].z * sc); o.w = f2bf(v[i].w * sc);
    *reinterpret_cast<ushort4*>(d + (lane16 + i * 16) * 4) = o;
  }
}

// counted-vmcnt barrier: wait own stage loads, align waves, pin scheduler
#define WB(N)                                                  \
  __builtin_amdgcn_sched_barrier(0);                           \
  asm volatile("s_waitcnt vmcnt(" #N ")" ::: "memory");        \
  __builtin_amdgcn_s_barrier();                                \
  __builtin_amdgcn_sched_barrier(0);

// stage one 64x128 A piece (16 KB) into ring buf; pointers advance per use
#define STAGE_P(BUF, P0, P1)                        \
  GLOAD_LDS16(P0, Sb + (BUF)*16384 + o0); P0 += 32768; \
  GLOAD_LDS16(P1, Sb + (BUF)*16384 + o1); P1 += 32768;

// 16 MFMA for one 128-K piece; FIRST=1 -> zero-C at kk==0 (per-tile acc init)
#define COMPUTE(BUF, H, FIRST)                                                        \
  {                                                                                   \
    __builtin_amdgcn_s_setprio(1);                                                    \
    _Pragma("unroll") for (int kk = 0; kk < 4; ++kk) {                                \
      short8_t afr[2];                                                                \
      const int cb = (kk & 1) * 64 + laneHi * 16;                                     \
      const int hh = kk >> 1;                                                         \
      _Pragma("unroll") for (int a = 0; a < 2; ++a) {                                 \
        int ra = wr * 32 + a * 16 + laneLo;                                           \
        afr[a] = *reinterpret_cast<const short8_t*>(                                  \
            Sb + (BUF)*16384 + hh * 8192 + ra * 128 + (cb ^ ((ra & 7) << 4)));        \
      }                                                                               \
      _Pragma("unroll") for (int a = 0; a < 2; ++a)                                   \
          _Pragma("unroll") for (int c = 0; c < 2; ++c)                               \
              acc[a][c] = __builtin_amdgcn_mfma_f32_16x16x32_bf16(                    \
                  afr[a], bfr[c][(H)*4 + kk],                                         \
                  ((FIRST) && kk == 0) ? f32x4{0.f, 0.f, 0.f, 0.f} : acc[a][c],       \
                  0, 0, 0);                                                           \
    }                                                                                 \
    __builtin_amdgcn_s_setprio(0);                                                    \
  }

// online-LSE epilogue over the finished tile (8 logits/lane per col-frag);
// bLp factored out (constant along reduction axis, applied in lse_finish)
#define EPILOGUE                                                                      \
  {                                                                                   \
    _Pragma("unroll") for (int c = 0; c < 2; ++c) {                                   \
      float w0 = acc[0][c][0] - av0.x, w1 = acc[0][c][1] - av0.y;                     \
      float w2 = acc[0][c][2] - av0.z, w3 = acc[0][c][3] - av0.w;                     \
      float w4 = acc[1][c][0] - av1.x, w5 = acc[1][c][1] - av1.y;                     \
      float w6 = acc[1][c][2] - av1.z, w7 = acc[1][c][3] - av1.w;                     \
      float mx = fmaxf(fmaxf(fmaxf(w0, w1), fmaxf(w2, w3)),                           \
                       fmaxf(fmaxf(w4, w5), fmaxf(w6, w7)));                          \
      float nm = fmaxf(m_run[c], mx);                                                 \
      float ss = fast_exp2(w0 - nm) + fast_exp2(w1 - nm) + fast_exp2(w2 - nm) +       \
                 fast_exp2(w3 - nm) + fast_exp2(w4 - nm) + fast_exp2(w5 - nm) +       \
                 fast_exp2(w6 - nm) + fast_exp2(w7 - nm);                             \
      s_run[c] = s_run[c] * fast_exp2(m_run[c] - nm) + ss;                            \
      m_run[c] = nm;                                                                  \
    }                                                                                 \
  }

#define ALOAD                                                  \
  av0 = *reinterpret_cast<const float4*>(aptr);                \
  av1 = *reinterpret_cast<const float4*>(aptr + 16);           \
  aptr += 64;

// Column-strip fused GEMM + online logsumexp, ring-4 LDS pipeline with
// counted vmcnt (no drains in main loop). 8 waves (2r x 4c), B in registers.
__global__ __launch_bounds__(512, 4) void gemm_lse_kernel(
    const unsigned short* __restrict__ Abf,  // [N][Z] scaled bf16 bits
    const unsigned short* __restrict__ Bbf,  // [M][Z]
    const float* __restrict__ nrm,           // [N+M]: k2*a2 then k2*b2
    float2* __restrict__ part,               // [NCH][M] (max2, sumexp2), bL-uncorrected
    int Mtot, int chRows) {
  __shared__ __align__(16) unsigned short S[4 * 8192];  // 64 KB ring (B panel staged through it)
  char* Sb = (char*)&S[0];

  const int tid = threadIdx.x;
  const int lane = tid & 63;
  const int w = tid >> 6;
  const int wr = w >> 2, wc = w & 3;
  const int laneLo = lane & 15, laneHi = lane >> 4;

  const int id = blockIdx.x;
  const int y = id & 7;     // XCD-affine: chunk y pinned to xcd id&7
  const int x = id >> 3;
  const int row0base = y * chRows;
  const int col0 = x * CG;

  // ---- stage full B panel (128 x 256 = 64 KB) into all of S, swizzled ----
#pragma unroll
  for (int i = 0; i < 8; ++i) {
    int o = i * 8192 + tid * 16;
    int r = o >> 9;
    int slot = (o >> 4) & 31;
    int sg = slot ^ (r & 7);  // flips low-3 slot bits only
    GLOAD_LDS16((const char*)Bbf + (size_t)(col0 + r) * 512 + sg * 16, Sb + o);
  }
  __syncthreads();
  short8_t bfr[2][8];
#pragma unroll
  for (int c = 0; c < 2; ++c) {
    int rb = wc * 32 + c * 16 + laneLo;
#pragma unroll
    for (int kk = 0; kk < 8; ++kk) {
      int cb = kk * 64 + laneHi * 16;
      bfr[c][kk] = *reinterpret_cast<const short8_t*>(Sb + rb * 512 + (cb ^ ((rb & 7) << 4)));
    }
  }
  __syncthreads();  // drains lgkm: bfr safely in regs before A-stages overwrite

  // ---- per-thread staging pointers (advance by RT*Z*2 = 32768 B per use) ----
  const int o0 = tid * 16, o1 = 8192 + tid * 16;
  const char* Ab8 = (const char*)Abf + (size_t)row0base * 512;
  int h0 = o0 >> 13, r0 = (o0 >> 7) & 63, g0 = ((o0 >> 4) & 7) ^ (r0 & 7);
  int h1 = o1 >> 13, r1 = (o1 >> 7) & 63, g1 = ((o1 >> 4) & 7) ^ (r1 & 7);
  const char* pE0 = Ab8 + r0 * 512 + h0 * 128 + g0 * 16;
  const char* pE1 = Ab8 + r1 * 512 + h1 * 128 + g1 * 16;
  const char* pO0 = pE0 + 256;
  const char* pO1 = pE1 + 256;
  const float* aptr = nrm + row0base + wr * 32 + laneHi * 4;

  f32x4 acc[2][2];
  float m_run[2] = {-1e30f, -1e30f};
  float s_run[2] = {0.f, 0.f};
  float4 av0, av1;

  // prologue: pieces 0(E,buf0), 1(O,buf1), 2(E,buf2)
  STAGE_P(0, pE0, pE1);
  STAGE_P(1, pO0, pO1);
  STAGE_P(2, pE0, pE1);

  // main: 128 pieces total (64 tiles x 2 K-halves); iteration uu handles
  // pieces 4uu..4uu+3 and stages 4uu+3..4uu+6. 31 iters + 4-piece tail = 128.
  for (int uu = 0; uu < 31; ++uu) {
    WB(4);  COMPUTE(0, 0, 1);  ALOAD;  STAGE_P(3, pO0, pO1);
    WB(6);  COMPUTE(1, 1, 0);  EPILOGUE;  STAGE_P(0, pE0, pE1);
    WB(4);  COMPUTE(2, 0, 1);  ALOAD;  STAGE_P(1, pO0, pO1);
    WB(6);  COMPUTE(3, 1, 0);  EPILOGUE;  STAGE_P(2, pE0, pE1);
  }
  // tail: pieces 124..127 (stage only piece 127)
  WB(4);  COMPUTE(0, 0, 1);  ALOAD;  STAGE_P(3, pO0, pO1);
  WB(6);  COMPUTE(1, 1, 0);  EPILOGUE;
  WB(2);  COMPUTE(2, 0, 1);  ALOAD;
  WB(2);  COMPUTE(3, 1, 0);  EPILOGUE;

  // ---- merge laneHi groups (shfl), then the two row-half waves (via S) ----
  __syncthreads();  // loop done; S reusable as reduction scratch
  float* redM = (float*)Sb;          // [2][128]
  float* redS = (float*)(Sb + 1024); // [2][128]
#pragma unroll
  for (int c = 0; c < 2; ++c) {
#pragma unroll
    for (int off = 16; off <= 32; off <<= 1) {
      float om = __shfl_xor(m_run[c], off);
      float os = __shfl_xor(s_run[c], off);
      float nm = fmaxf(m_run[c], om);
      s_run[c] = s_run[c] * fast_exp2(m_run[c] - nm) + os * fast_exp2(om - nm);
      m_run[c] = nm;
    }
    if (laneHi == 0) {
      redM[wr * 128 + wc * 32 + c * 16 + laneLo] = m_run[c];
      redS[wr * 128 + wc * 32 + c * 16 + laneLo] = s_run[c];
    }
  }
  __syncthreads();
  if (tid < CG) {
    float m0 = redM[tid], m1 = redM[128 + tid];
    float s0 = redS[tid], s1 = redS[128 + tid];
    float Mx = fmaxf(m0, m1);
    float Sx = s0 * fast_exp2(m0 - Mx) + s1 * fast_exp2(m1 - Mx);
    part[(size_t)y * Mtot + col0 + tid] = make_float2(Mx, Sx);
  }
}

// Single block: merge NCH partials/col, subtract bL, lse, reduce, write.
__global__ __launch_bounds__(1024) void lse_finish(const float2* __restrict__ part,
                                                   const float* __restrict__ bLp,
                                                   int NB, int Mtot,
                                                   float* __restrict__ out) {
  float accv = 0.f;
#pragma unroll
  for (int i = 0; i < 8; ++i) {
    int m = i * 1024 + threadIdx.x;
    float mx = -1e30f, s = 0.f;
    for (int b = 0; b < NB; ++b) {
      float2 p = part[(size_t)b * Mtot + m];
      float nm = fmaxf(mx, p.x);
      s = s * fast_exp2(mx - nm) + p.y * fast_exp2(p.x - nm);
      mx = nm;
    }
    accv += mx + __log2f(s) - bLp[m];
  }
#pragma unroll
  for (int off = 32; off >= 1; off >>= 1) accv += __shfl_xor(accv, off);
  __shared__ float red[16];
  if ((threadIdx.x & 63) == 0) red[threadIdx.x >> 6] = accv;
  __syncthreads();
  if (threadIdx.x == 0) {
    float t = 0.f;
#pragma unroll
    for (int i = 0; i < 16; ++i) t += red[i];
    out[0] = -LN2 * t / (float)Mtot;
  }
}

extern "C" void kernel_launch(void* const* d_in, const int* in_sizes, int n_in,
                              void* d_out, int out_size, void* d_ws, size_t ws_size,
                              hipStream_t stream) {
  const float* mean = (const float*)d_in[0];
  const float* e    = (const float*)d_in[1];
  const int* sigma  = (const int*)d_in[2];
  const int N_ = in_sizes[0] / Z;  // 32768
  const int M_ = in_sizes[1] / Z;  // 8192
  const int chRows = N_ / NCH;     // 4096

  char* ws = (char*)d_ws;
  unsigned short* Abf = (unsigned short*)ws; ws += (size_t)N_ * Z * sizeof(unsigned short);
  unsigned short* Bbf = (unsigned short*)ws; ws += (size_t)M_ * Z * sizeof(unsigned short);
  float* nrm = (float*)ws;                   ws += (size_t)(N_ + M_) * sizeof(float);
  float2* part = (float2*)ws;                // NCH * M_ float2 = 512 KB

  prep_kernel<<<(N_ + M_) / 16, 256, 0, stream>>>(mean, e, Abf, Bbf, nrm, sigma, N_, M_);
  gemm_lse_kernel<<<(M_ / CG) * NCH, 512, 0, stream>>>(Abf, Bbf, nrm, part, M_, chRows);
  lse_finish<<<1, 1024, 0, stream>>>(part, nrm + N_, NCH, M_, (float*)d_out);
}

// Round 6
// 232.900 us; speedup vs baseline: 1.3945x; 1.3945x over previous
//
#include <hip/hip_runtime.h>
#include <hip/hip_bf16.h>
#include <cstdint>
#include <cstddef>

#define Z 256      // latent dim (K)
#define CG 128     // e-columns per block
#define RT 64      // mean-rows per tile
#define NCH 8      // N chunks (grid = 64 x 8 = 512 = exactly 2 blocks/CU)
#define LOG2E 1.4426950408889634f
#define LN2 0.6931471805599453f

typedef __attribute__((ext_vector_type(8))) short short8_t;
typedef __attribute__((ext_vector_type(4))) float f32x4;

#define GLOAD_LDS16(g, l)                                                              \
  __builtin_amdgcn_global_load_lds((const __attribute__((address_space(1))) void*)(g), \
                                   (__attribute__((address_space(3))) void*)(l), 16, 0, 0)

__device__ __forceinline__ unsigned short f2bf(float x) {
  __hip_bfloat16 h = __float2bfloat16(x);
  return *reinterpret_cast<unsigned short*>(&h);
}

__device__ __forceinline__ float fast_exp2(float x) {
#if __has_builtin(__builtin_amdgcn_exp2f)
  return __builtin_amdgcn_exp2f(x);
#else
  float r;
  asm("v_exp_f32 %0, %1" : "=v"(r) : "v"(x));
  return r;
#endif
}

// prep: fp32 -> bf16 scaled by sqrt(c1), plus k2 * row-sum-of-squares.
// 32 lanes per row (32B in / 16B out per lane), 8 rows per 256-thr block.
__global__ __launch_bounds__(256) void prep_kernel(const float* __restrict__ mean,
                                                   const float* __restrict__ e,
                                                   unsigned short* __restrict__ Abf,
                                                   unsigned short* __restrict__ Bbf,
                                                   float* __restrict__ nrm,
                                                   const int* __restrict__ sigma_p,
                                                   int Nr, int Mr) {
  const float sgm = (float)(*sigma_p);
  const float c1 = LOG2E / (sgm * sgm);
  const float k2 = 0.5f * c1;
  const float sc = sqrtf(c1);
  const int tid = threadIdx.x;
  const int lane32 = tid & 31;
  const int row = blockIdx.x * 8 + (tid >> 5);
  if (row >= Nr + Mr) return;
  const float* src = (row < Nr) ? (mean + (size_t)row * Z) : (e + (size_t)(row - Nr) * Z);
  unsigned short* d = (row < Nr) ? (Abf + (size_t)row * Z) : (Bbf + (size_t)(row - Nr) * Z);
  const float4 v0 = *reinterpret_cast<const float4*>(src + lane32 * 8);
  const float4 v1 = *reinterpret_cast<const float4*>(src + lane32 * 8 + 4);
  float s = v0.x * v0.x + v0.y * v0.y + v0.z * v0.z + v0.w * v0.w +
            v1.x * v1.x + v1.y * v1.y + v1.z * v1.z + v1.w * v1.w;
  s += __shfl_xor(s, 1); s += __shfl_xor(s, 2); s += __shfl_xor(s, 4);
  s += __shfl_xor(s, 8); s += __shfl_xor(s, 16);
  if (lane32 == 0) nrm[row] = k2 * s;
  short8_t o;
  o[0] = f2bf(v0.x * sc); o[1] = f2bf(v0.y * sc);
  o[2] = f2bf(v0.z * sc); o[3] = f2bf(v0.w * sc);
  o[4] = f2bf(v1.x * sc); o[5] = f2bf(v1.y * sc);
  o[6] = f2bf(v1.z * sc); o[7] = f2bf(v1.w * sc);
  *reinterpret_cast<short8_t*>(d + lane32 * 8) = o;
}

// stage one full 64-row x 256-K tile (32 KB) into buffer BUF (literal 0/1).
// LDS layout: 4 chunks (K-quarters) of [64 rows][128 B], XOR-swizzled source.
#define STAGE_TILE(BUF, T)                                  \
  {                                                         \
    const char* g = Ab8 + (size_t)(T) * 32768;              \
    char* l = Sb + (BUF) * 32768 + tid * 16;                \
    GLOAD_LDS16(g + gof0, l);                               \
    GLOAD_LDS16(g + gof1, l + 8192);                        \
    GLOAD_LDS16(g + gof2, l + 16384);                       \
    GLOAD_LDS16(g + gof3, l + 24576);                       \
  }

// 32 MFMA for one full tile from buffer BUF (literal): 8 k32-steps x 2r x 2c.
// acc starts from zero at kk4==0 (no separate zero-init movs).
#define COMPUTE_TILE(BUF)                                                             \
  {                                                                                   \
    _Pragma("unroll") for (int kk4 = 0; kk4 < 8; ++kk4) {                             \
      short8_t afr[2];                                                                \
      const int cb = (kk4 & 1) * 64 + laneHi * 16;                                    \
      const int ch = kk4 >> 1;                                                        \
      _Pragma("unroll") for (int a = 0; a < 2; ++a) {                                 \
        int ra = wr * 32 + a * 16 + laneLo;                                           \
        afr[a] = *reinterpret_cast<const short8_t*>(                                  \
            Sb + (BUF) * 32768 + ch * 8192 + ra * 128 + (cb ^ ((ra & 7) << 4)));      \
      }                                                                               \
      _Pragma("unroll") for (int a = 0; a < 2; ++a)                                   \
          _Pragma("unroll") for (int c = 0; c < 2; ++c)                               \
              acc[a][c] = __builtin_amdgcn_mfma_f32_16x16x32_bf16(                    \
                  afr[a], bfr[c][kk4],                                                \
                  (kk4 == 0) ? f32x4{0.f, 0.f, 0.f, 0.f} : acc[a][c], 0, 0, 0);       \
    }                                                                                 \
  }

// online-LSE over the finished tile: 8 logits/lane per col-frag (pre-scaled,
// per-column b2 term factored out -> applied in lse_finish)
#define EPILOGUE                                                                      \
  {                                                                                   \
    _Pragma("unroll") for (int c = 0; c < 2; ++c) {                                   \
      float w0 = acc[0][c][0] - av0.x, w1 = acc[0][c][1] - av0.y;                     \
      float w2 = acc[0][c][2] - av0.z, w3 = acc[0][c][3] - av0.w;                     \
      float w4 = acc[1][c][0] - av1.x, w5 = acc[1][c][1] - av1.y;                     \
      float w6 = acc[1][c][2] - av1.z, w7 = acc[1][c][3] - av1.w;                     \
      float mx = fmaxf(fmaxf(fmaxf(w0, w1), fmaxf(w2, w3)),                           \
                       fmaxf(fmaxf(w4, w5), fmaxf(w6, w7)));                          \
      float nm = fmaxf(m_run[c], mx);                                                 \
      float ss = fast_exp2(w0 - nm) + fast_exp2(w1 - nm) + fast_exp2(w2 - nm) +       \
                 fast_exp2(w3 - nm) + fast_exp2(w4 - nm) + fast_exp2(w5 - nm) +       \
                 fast_exp2(w6 - nm) + fast_exp2(w7 - nm);                             \
      s_run[c] = s_run[c] * fast_exp2(m_run[c] - nm) + ss;                            \
      m_run[c] = nm;                                                                  \
    }                                                                                 \
  }

#define ALOAD                                                  \
  av0 = *reinterpret_cast<const float4*>(aptr);                \
  av1 = *reinterpret_cast<const float4*>(aptr + 16);           \
  aptr += 64;

// Column-strip fused GEMM + online logsumexp. Full-tile double buffer,
// ONE __syncthreads per tile (compiler-scheduled; no asm waits).
// 8 waves (2r x 4c), B panel (32 cols x K=256 per wave) register-resident.
__global__ __launch_bounds__(512, 4) void gemm_lse_kernel(
    const unsigned short* __restrict__ Abf,  // [N][Z] scaled bf16 bits
    const unsigned short* __restrict__ Bbf,  // [M][Z]
    const float* __restrict__ nrm,           // [N+M]: k2*a2 then k2*b2
    float2* __restrict__ part,               // [NCH][M] (max2, sumexp2), b2-uncorrected
    int Mtot, int chRows) {
  __shared__ __align__(16) unsigned short S[2][RT * Z];  // 64 KB: 2 x full tile
  char* Sb = (char*)&S[0][0];

  const int tid = threadIdx.x;
  const int lane = tid & 63;
  const int w = tid >> 6;
  const int wr = w >> 2, wc = w & 3;
  const int laneLo = lane & 15, laneHi = lane >> 4;

  const int id = blockIdx.x;
  const int y = id & 7;     // XCD-affine: chunk y pinned to xcd id&7
  const int x = id >> 3;
  const int row0base = y * chRows;
  const int col0 = x * CG;
  const int ntiles = chRows / RT;  // 64

  // ---- stage full B panel (128 x 256 = 64 KB) into all of S, swizzled ----
#pragma unroll
  for (int i = 0; i < 8; ++i) {
    int o = i * 8192 + tid * 16;
    int r = o >> 9;
    int slot = (o >> 4) & 31;
    int sg = slot ^ (r & 7);  // flips low-3 slot bits only
    GLOAD_LDS16((const char*)Bbf + (size_t)(col0 + r) * 512 + sg * 16, Sb + o);
  }
  __syncthreads();
  short8_t bfr[2][8];
#pragma unroll
  for (int c = 0; c < 2; ++c) {
    int rb = wc * 32 + c * 16 + laneLo;
#pragma unroll
    for (int kk = 0; kk < 8; ++kk) {
      int cb = kk * 64 + laneHi * 16;
      bfr[c][kk] = *reinterpret_cast<const short8_t*>(Sb + rb * 512 + (cb ^ ((rb & 7) << 4)));
    }
  }
  __syncthreads();  // bfr safely in regs before A-stages overwrite S

  // ---- per-thread precomputed A staging offsets (4 chunk loads/tile) ----
  const char* Ab8 = (const char*)Abf + (size_t)row0base * 512;
  const int ar = (tid * 16) >> 7;                 // row this thread stages (0..63)
  const int asl = (tid * 16 >> 4) & 7;            // 16B slot within 128B chunk-row
  const int asg = asl ^ (ar & 7);                 // swizzled source slot
  const int gof0 = ar * 512 + 0 * 128 + asg * 16;
  const int gof1 = ar * 512 + 1 * 128 + asg * 16;
  const int gof2 = ar * 512 + 2 * 128 + asg * 16;
  const int gof3 = ar * 512 + 3 * 128 + asg * 16;
  const float* aptr = nrm + row0base + wr * 32 + laneHi * 4;

  f32x4 acc[2][2];
  float m_run[2] = {-1e30f, -1e30f};
  float s_run[2] = {0.f, 0.f};
  float4 av0, av1;

  STAGE_TILE(0, 0);
  __syncthreads();  // tile 0 resident

  for (int tp = 0; tp < ntiles / 2; ++tp) {
    const int t = tp * 2;
    // even tile (buf 0); prefetch odd tile into buf 1
    STAGE_TILE(1, t + 1);
    ALOAD;
    COMPUTE_TILE(0);
    EPILOGUE;
    __syncthreads();
    // odd tile (buf 1); prefetch next even tile into buf 0
    if (tp + 1 < ntiles / 2) STAGE_TILE(0, t + 2);
    ALOAD;
    COMPUTE_TILE(1);
    EPILOGUE;
    __syncthreads();
  }

  // ---- merge laneHi groups (shfl), then the two row-half waves (via S) ----
  float* redM = (float*)Sb;          // [2][128]
  float* redS = (float*)(Sb + 1024); // [2][128]
#pragma unroll
  for (int c = 0; c < 2; ++c) {
#pragma unroll
    for (int off = 16; off <= 32; off <<= 1) {
      float om = __shfl_xor(m_run[c], off);
      float os = __shfl_xor(s_run[c], off);
      float nm = fmaxf(m_run[c], om);
      s_run[c] = s_run[c] * fast_exp2(m_run[c] - nm) + os * fast_exp2(om - nm);
      m_run[c] = nm;
    }
    if (laneHi == 0) {
      redM[wr * 128 + wc * 32 + c * 16 + laneLo] = m_run[c];
      redS[wr * 128 + wc * 32 + c * 16 + laneLo] = s_run[c];
    }
  }
  __syncthreads();
  if (tid < CG) {
    float m0 = redM[tid], m1 = redM[128 + tid];
    float s0 = redS[tid], s1 = redS[128 + tid];
    float Mx = fmaxf(m0, m1);
    float Sx = s0 * fast_exp2(m0 - Mx) + s1 * fast_exp2(m1 - Mx);
    part[(size_t)y * Mtot + col0 + tid] = make_float2(Mx, Sx);
  }
}

// Single block: merge NCH partials/col, subtract b2 term, lse, reduce, write.
__global__ __launch_bounds__(1024) void lse_finish(const float2* __restrict__ part,
                                                   const float* __restrict__ bLp,
                                                   int NB, int Mtot,
                                                   float* __restrict__ out) {
  float accv = 0.f;
#pragma unroll
  for (int i = 0; i < 8; ++i) {
    int m = i * 1024 + threadIdx.x;
    float mx = -1e30f, s = 0.f;
    for (int b = 0; b < NB; ++b) {
      float2 p = part[(size_t)b * Mtot + m];
      float nm = fmaxf(mx, p.x);
      s = s * fast_exp2(mx - nm) + p.y * fast_exp2(p.x - nm);
      mx = nm;
    }
    accv += mx + __log2f(s) - bLp[m];
  }
#pragma unroll
  for (int off = 32; off >= 1; off >>= 1) accv += __shfl_xor(accv, off);
  __shared__ float red[16];
  if ((threadIdx.x & 63) == 0) red[threadIdx.x >> 6] = accv;
  __syncthreads();
  if (threadIdx.x == 0) {
    float t = 0.f;
#pragma unroll
    for (int i = 0; i < 16; ++i) t += red[i];
    out[0] = -LN2 * t / (float)Mtot;
  }
}

extern "C" void kernel_launch(void* const* d_in, const int* in_sizes, int n_in,
                              void* d_out, int out_size, void* d_ws, size_t ws_size,
                              hipStream_t stream) {
  const float* mean = (const float*)d_in[0];
  const float* e    = (const float*)d_in[1];
  const int* sigma  = (const int*)d_in[2];
  const int N_ = in_sizes[0] / Z;  // 32768
  const int M_ = in_sizes[1] / Z;  // 8192
  const int chRows = N_ / NCH;     // 4096

  char* ws = (char*)d_ws;
  unsigned short* Abf = (unsigned short*)ws; ws += (size_t)N_ * Z * sizeof(unsigned short);
  unsigned short* Bbf = (unsigned short*)ws; ws += (size_t)M_ * Z * sizeof(unsigned short);
  float* nrm = (float*)ws;                   ws += (size_t)(N_ + M_) * sizeof(float);
  float2* part = (float2*)ws;                // NCH * M_ float2 = 512 KB

  prep_kernel<<<(N_ + M_) / 8, 256, 0, stream>>>(mean, e, Abf, Bbf, nrm, sigma, N_, M_);
  gemm_lse_kernel<<<(M_ / CG) * NCH, 512, 0, stream>>>(Abf, Bbf, nrm, part, M_, chRows);
  lse_finish<<<1, 1024, 0, stream>>>(part, nrm + N_, NCH, M_, (float*)d_out);
}

// Round 7
// 185.445 us; speedup vs baseline: 1.7513x; 1.2559x over previous
//
#include <hip/hip_runtime.h>
#include <hip/hip_bf16.h>
#include <cstdint>
#include <cstddef>

#define Z 256      // latent dim (K); also bytes per fp8 row
#define CG 128     // e-columns per block
#define RT 64      // mean-rows per tile
#define NCH 8      // N chunks (grid = 64 x 8 = 512 = exactly 2 blocks/CU)
#define LOG2E 1.4426950408889634f
#define LN2 0.6931471805599453f

typedef __attribute__((ext_vector_type(4))) float f32x4;
typedef long long fp8v8;  // 8 fp8 bytes = 2 VGPR (MFMA A/B operand)

#define GLOAD_LDS16(g, l)                                                              \
  __builtin_amdgcn_global_load_lds((const __attribute__((address_space(1))) void*)(g), \
                                   (__attribute__((address_space(3))) void*)(l), 16, 0, 0)

__device__ __forceinline__ float fast_exp2(float x) {
#if __has_builtin(__builtin_amdgcn_exp2f)
  return __builtin_amdgcn_exp2f(x);
#else
  float r;
  asm("v_exp_f32 %0, %1" : "=v"(r) : "v"(x));
  return r;
#endif
}

// prep: fp32 -> fp8 e4m3 scaled by sqrt(c1), plus k2 * row-sum-of-squares
// (norms stay exact fp32). 8 rows per 256-thr block, 32 lanes/row.
__global__ __launch_bounds__(256) void prep_kernel(const float* __restrict__ mean,
                                                   const float* __restrict__ e,
                                                   unsigned char* __restrict__ Abf,
                                                   unsigned char* __restrict__ Bbf,
                                                   float* __restrict__ nrm,
                                                   const int* __restrict__ sigma_p,
                                                   int Nr, int Mr) {
  const float sgm = (float)(*sigma_p);
  const float c1 = LOG2E / (sgm * sgm);
  const float k2 = 0.5f * c1;
  const float sc = sqrtf(c1);
  const int tid = threadIdx.x;
  const int lane32 = tid & 31;
  const int row = blockIdx.x * 8 + (tid >> 5);
  if (row >= Nr + Mr) return;
  const float* src = (row < Nr) ? (mean + (size_t)row * Z) : (e + (size_t)(row - Nr) * Z);
  unsigned char* d = (row < Nr) ? (Abf + (size_t)row * Z) : (Bbf + (size_t)(row - Nr) * Z);
  const float4 v0 = *reinterpret_cast<const float4*>(src + lane32 * 8);
  const float4 v1 = *reinterpret_cast<const float4*>(src + lane32 * 8 + 4);
  float s = v0.x * v0.x + v0.y * v0.y + v0.z * v0.z + v0.w * v0.w +
            v1.x * v1.x + v1.y * v1.y + v1.z * v1.z + v1.w * v1.w;
  s += __shfl_xor(s, 1); s += __shfl_xor(s, 2); s += __shfl_xor(s, 4);
  s += __shfl_xor(s, 8); s += __shfl_xor(s, 16);
  if (lane32 == 0) nrm[row] = k2 * s;
  int r0 = __builtin_amdgcn_cvt_pk_fp8_f32(v0.x * sc, v0.y * sc, 0, false);
  r0 = __builtin_amdgcn_cvt_pk_fp8_f32(v0.z * sc, v0.w * sc, r0, true);
  int r1 = __builtin_amdgcn_cvt_pk_fp8_f32(v1.x * sc, v1.y * sc, 0, false);
  r1 = __builtin_amdgcn_cvt_pk_fp8_f32(v1.z * sc, v1.w * sc, r1, true);
  *reinterpret_cast<int2*>(d + lane32 * 8) = make_int2(r0, r1);
}

// stage one full 64-row x 256-B fp8 A tile (16 KB) into buffer BUF (literal 0/1).
// LDS rows of 256 B; source pre-swizzled: 16B-slot p -> p ^ (row&7).
#define STAGE_TILE(BUF, T)                                  \
  {                                                         \
    const char* g = Ab8 + (size_t)(T) * 16384;              \
    GLOAD_LDS16(g + gof0, Sb + (BUF) * 16384 + o0);         \
    GLOAD_LDS16(g + gof1, Sb + (BUF) * 16384 + o1);         \
  }

// 32 MFMA for one tile from buffer BUF: 8 k32-steps x 2 row-frags x 2 col-frags.
// A-frag = 8 fp8 (ds_read_b64), swizzled slot16 ^ (row&7) -> 2 lanes/bank (free).
#define COMPUTE_TILE(BUF)                                                               \
  {                                                                                     \
    _Pragma("unroll") for (int kk = 0; kk < 8; ++kk) {                                  \
      fp8v8 afr[2];                                                                     \
      const int s8 = kk * 4 + laneHi;                                                   \
      _Pragma("unroll") for (int a = 0; a < 2; ++a) {                                   \
        const int ro = wr * 32 + a * 16 + laneLo;                                       \
        const int addr = ro * 256 + ((((s8 >> 1) ^ (ro & 7)) << 4) | ((s8 & 1) << 3));  \
        afr[a] = *reinterpret_cast<const fp8v8*>(Sb + (BUF) * 16384 + addr);            \
      }                                                                                 \
      _Pragma("unroll") for (int a = 0; a < 2; ++a)                                     \
          _Pragma("unroll") for (int c = 0; c < 2; ++c)                                 \
              acc[a][c] = __builtin_amdgcn_mfma_f32_16x16x32_fp8_fp8(                   \
                  afr[a], bfr[c][kk],                                                   \
                  (kk == 0) ? f32x4{0.f, 0.f, 0.f, 0.f} : acc[a][c], 0, 0, 0);          \
    }                                                                                   \
  }

// online-LSE over the finished tile: 8 logits/lane per col-frag (pre-scaled;
// per-column b2 term factored out -> applied in lse_finish)
#define EPILOGUE                                                                      \
  {                                                                                   \
    _Pragma("unroll") for (int c = 0; c < 2; ++c) {                                   \
      float w0 = acc[0][c][0] - av0.x, w1 = acc[0][c][1] - av0.y;                     \
      float w2 = acc[0][c][2] - av0.z, w3 = acc[0][c][3] - av0.w;                     \
      float w4 = acc[1][c][0] - av1.x, w5 = acc[1][c][1] - av1.y;                     \
      float w6 = acc[1][c][2] - av1.z, w7 = acc[1][c][3] - av1.w;                     \
      float mx = fmaxf(fmaxf(fmaxf(w0, w1), fmaxf(w2, w3)),                           \
                       fmaxf(fmaxf(w4, w5), fmaxf(w6, w7)));                          \
      float nm = fmaxf(m_run[c], mx);                                                 \
      float ss = fast_exp2(w0 - nm) + fast_exp2(w1 - nm) + fast_exp2(w2 - nm) +       \
                 fast_exp2(w3 - nm) + fast_exp2(w4 - nm) + fast_exp2(w5 - nm) +       \
                 fast_exp2(w6 - nm) + fast_exp2(w7 - nm);                             \
      s_run[c] = s_run[c] * fast_exp2(m_run[c] - nm) + ss;                            \
      m_run[c] = nm;                                                                  \
    }                                                                                 \
  }

#define ALOAD                                                  \
  av0 = *reinterpret_cast<const float4*>(aptr);                \
  av1 = *reinterpret_cast<const float4*>(aptr + 16);           \
  aptr += 64;

// Column-strip fused GEMM (fp8 e4m3) + online logsumexp. Full-tile double
// buffer (2x16 KB), ONE __syncthreads per tile, compiler-scheduled.
// 8 waves (2r x 4c); B panel (32 cols x K=256 fp8 per wave) register-resident.
__global__ __launch_bounds__(512, 4) void gemm_lse_kernel(
    const unsigned char* __restrict__ Abf,  // [N][Z] fp8, pre-scaled by sqrt(c1)
    const unsigned char* __restrict__ Bbf,  // [M][Z] fp8
    const float* __restrict__ nrm,          // [N+M]: k2*a2 then k2*b2
    float2* __restrict__ part,              // [NCH][M] (max2, sumexp2), b2-uncorrected
    int Mtot, int chRows) {
  __shared__ __align__(16) char Sb[32768];  // B staged through it, then A dbuf

  const int tid = threadIdx.x;
  const int lane = tid & 63;
  const int w = tid >> 6;
  const int wr = w >> 2, wc = w & 3;
  const int laneLo = lane & 15, laneHi = lane >> 4;

  const int id = blockIdx.x;
  const int y = id & 7;     // XCD-affine: chunk y pinned to xcd id&7
  const int x = id >> 3;
  const int row0base = y * chRows;
  const int col0 = x * CG;
  const int ntiles = chRows / RT;  // 64

  // ---- stage full B panel (128 cols x 256 B = 32 KB), swizzled source ----
#pragma unroll
  for (int i = 0; i < 4; ++i) {
    int o = i * 8192 + tid * 16;
    int r = o >> 8;
    int p = (o >> 4) & 15;
    GLOAD_LDS16((const char*)Bbf + (size_t)(col0 + r) * Z + ((p ^ (r & 7)) << 4),
                Sb + o);
  }
  __syncthreads();
  fp8v8 bfr[2][8];
#pragma unroll
  for (int c = 0; c < 2; ++c) {
    const int rb = wc * 32 + c * 16 + laneLo;
#pragma unroll
    for (int kk = 0; kk < 8; ++kk) {
      const int s8 = kk * 4 + laneHi;
      const int addr = rb * 256 + ((((s8 >> 1) ^ (rb & 7)) << 4) | ((s8 & 1) << 3));
      bfr[c][kk] = *reinterpret_cast<const fp8v8*>(Sb + addr);
    }
  }
  __syncthreads();  // bfr safely in regs before A-stages overwrite Sb

  // ---- per-thread A staging offsets (2 gload_lds per tile) ----
  const char* Ab8 = (const char*)Abf + (size_t)row0base * Z;
  const int o0 = tid * 16, o1 = 8192 + tid * 16;
  const int r_0 = o0 >> 8, p_0 = (o0 >> 4) & 15;
  const int r_1 = o1 >> 8, p_1 = (o1 >> 4) & 15;
  const int gof0 = r_0 * 256 + ((p_0 ^ (r_0 & 7)) << 4);
  const int gof1 = r_1 * 256 + ((p_1 ^ (r_1 & 7)) << 4);
  const float* aptr = nrm + row0base + wr * 32 + laneHi * 4;

  f32x4 acc[2][2];
  float m_run[2] = {-1e30f, -1e30f};
  float s_run[2] = {0.f, 0.f};
  float4 av0, av1;

  STAGE_TILE(0, 0);
  __syncthreads();  // tile 0 resident

  for (int tp = 0; tp < ntiles / 2; ++tp) {
    const int t = tp * 2;
    // even tile (buf 0); prefetch odd tile into buf 1
    STAGE_TILE(1, t + 1);
    ALOAD;
    COMPUTE_TILE(0);
    EPILOGUE;
    __syncthreads();
    // odd tile (buf 1); prefetch next even tile into buf 0
    if (tp + 1 < ntiles / 2) STAGE_TILE(0, t + 2);
    ALOAD;
    COMPUTE_TILE(1);
    EPILOGUE;
    __syncthreads();
  }

  // ---- merge laneHi groups (shfl), then the two row-half waves (via Sb) ----
  float* redM = (float*)Sb;            // [2][128]
  float* redS = (float*)(Sb + 1024);   // [2][128]
#pragma unroll
  for (int c = 0; c < 2; ++c) {
#pragma unroll
    for (int off = 16; off <= 32; off <<= 1) {
      float om = __shfl_xor(m_run[c], off);
      float os = __shfl_xor(s_run[c], off);
      float nm = fmaxf(m_run[c], om);
      s_run[c] = s_run[c] * fast_exp2(m_run[c] - nm) + os * fast_exp2(om - nm);
      m_run[c] = nm;
    }
    if (laneHi == 0) {
      redM[wr * 128 + wc * 32 + c * 16 + laneLo] = m_run[c];
      redS[wr * 128 + wc * 32 + c * 16 + laneLo] = s_run[c];
    }
  }
  __syncthreads();
  if (tid < CG) {
    float m0 = redM[tid], m1 = redM[128 + tid];
    float s0 = redS[tid], s1 = redS[128 + tid];
    float Mx = fmaxf(m0, m1);
    float Sx = s0 * fast_exp2(m0 - Mx) + s1 * fast_exp2(m1 - Mx);
    part[(size_t)y * Mtot + col0 + tid] = make_float2(Mx, Sx);
  }
}

// 32 blocks: merge NCH partials/col, subtract b2 term, lse, reduce, atomicAdd.
__global__ __launch_bounds__(256) void lse_finish(const float2* __restrict__ part,
                                                  const float* __restrict__ bLp,
                                                  int NB, int Mtot,
                                                  float* __restrict__ out) {
  const int m = blockIdx.x * blockDim.x + threadIdx.x;
  float mx = -1e30f, s = 0.f;
  for (int b = 0; b < NB; ++b) {
    float2 p = part[(size_t)b * Mtot + m];
    float nm = fmaxf(mx, p.x);
    s = s * fast_exp2(mx - nm) + p.y * fast_exp2(p.x - nm);
    mx = nm;
  }
  float v = mx + __log2f(s) - bLp[m];
#pragma unroll
  for (int off = 32; off >= 1; off >>= 1) v += __shfl_xor(v, off);
  __shared__ float red[4];
  if ((threadIdx.x & 63) == 0) red[threadIdx.x >> 6] = v;
  __syncthreads();
  if (threadIdx.x == 0)
    atomicAdd(out, -LN2 * (red[0] + red[1] + red[2] + red[3]) / (float)Mtot);
}

extern "C" void kernel_launch(void* const* d_in, const int* in_sizes, int n_in,
                              void* d_out, int out_size, void* d_ws, size_t ws_size,
                              hipStream_t stream) {
  const float* mean = (const float*)d_in[0];
  const float* e    = (const float*)d_in[1];
  const int* sigma  = (const int*)d_in[2];
  const int N_ = in_sizes[0] / Z;  // 32768
  const int M_ = in_sizes[1] / Z;  // 8192
  const int chRows = N_ / NCH;     // 4096

  char* ws = (char*)d_ws;
  unsigned char* Abf = (unsigned char*)ws; ws += (size_t)N_ * Z;
  unsigned char* Bbf = (unsigned char*)ws; ws += (size_t)M_ * Z;
  float* nrm = (float*)ws;                 ws += (size_t)(N_ + M_) * sizeof(float);
  float2* part = (float2*)ws;              // NCH * M_ float2 = 512 KB

  hipMemsetAsync(d_out, 0, sizeof(float), stream);
  prep_kernel<<<(N_ + M_) / 8, 256, 0, stream>>>(mean, e, Abf, Bbf, nrm, sigma, N_, M_);
  gemm_lse_kernel<<<(M_ / CG) * NCH, 512, 0, stream>>>(Abf, Bbf, nrm, part, M_, chRows);
  lse_finish<<<M_ / 256, 256, 0, stream>>>(part, nrm + N_, NCH, M_, (float*)d_out);
}